// Round 1
// baseline (403.594 us; speedup 1.0000x reference)
//
#include <hip/hip_runtime.h>

// PetaloMixer: LN -> 4x shared-weight Mamba over parts -> skip -> LN -> proj
// B=2, C=256, L=4096, P=4 parts, DM=64, DI=128, DS=16, DTR=4, OUT=256
// All fp32. Chunked parallel scan: NCH=32 chunks of CHL=128 steps.

#define B_    2
#define C_    256
#define L_    4096
#define P_    4
#define DM_   64
#define DI_   128
#define DS_   16
#define OUT_  256
#define NCH   32
#define CHL   128
#define TS    64

// ---------------- K1: LayerNorm over C for (b,l), x is (b,c,l) ----------------
__global__ __launch_bounds__(256) void k1_ln(const float* __restrict__ x,
        const float* __restrict__ g, const float* __restrict__ bb,
        float* __restrict__ xn) {
  __shared__ float tile[256][33];
  __shared__ float psum[8][32];
  __shared__ float psq[8][32];
  __shared__ float smu[32], srs[32];
  int t = threadIdx.x;
  int l0 = blockIdx.x * 32;
  int b = blockIdx.y;
  const float* xb = x + (size_t)b * C_ * L_;
  int ll = t & 31, cr = t >> 5;
  for (int i = 0; i < 32; ++i) {
    int c = cr + 8 * i;
    tile[c][ll] = xb[(size_t)c * L_ + l0 + ll];
  }
  __syncthreads();
  {
    int l = t & 31, k = t >> 5;
    float s = 0.f, sq = 0.f;
    #pragma unroll 8
    for (int j = 0; j < 32; ++j) {
      float v = tile[32 * k + j][l];
      s += v; sq += v * v;
    }
    psum[k][l] = s; psq[k][l] = sq;
  }
  __syncthreads();
  if (t < 32) {
    float s = 0.f, sq = 0.f;
    #pragma unroll
    for (int k = 0; k < 8; ++k) { s += psum[k][t]; sq += psq[k][t]; }
    float mu = s * (1.f / 256.f);
    float var = sq * (1.f / 256.f) - mu * mu;
    smu[t] = mu;
    srs[t] = rsqrtf(var + 1e-5f);
  }
  __syncthreads();
  float gc = g[t], bc = bb[t];
  for (int l = 0; l < 32; ++l) {
    float v = (tile[t][l] - smu[l]) * srs[l] * gc + bc;
    xn[((size_t)b * L_ + l0 + l) * C_ + t] = v;
  }
}

// ---------------- K2: xz[b,p,l,0:256] = xn_part[b,l,64] @ W(256x64)^T --------
__global__ __launch_bounds__(256) void k2_inproj(const float* __restrict__ xn,
        const float* __restrict__ w, float* __restrict__ xz) {
  __shared__ float sw[256][65];
  __shared__ float sx[64][64];
  int t = threadIdx.x;
  int l0 = blockIdx.x * 64;
  int p = blockIdx.y, b = blockIdx.z;
  for (int i = 0; i < 64; ++i) {
    int idx = t + 256 * i;
    sw[idx >> 6][idx & 63] = w[idx];
  }
  for (int i = 0; i < 16; ++i) {
    int idx = t + 256 * i;
    int ll = idx >> 6, dm = idx & 63;
    sx[ll][dm] = xn[((size_t)b * L_ + l0 + ll) * C_ + p * DM_ + dm];
  }
  __syncthreads();
  size_t obase = ((size_t)(b * P_ + p) * L_ + l0) * 256 + t;
  for (int lb = 0; lb < 4; ++lb) {
    float acc[16];
    #pragma unroll
    for (int j = 0; j < 16; ++j) acc[j] = 0.f;
    for (int dm = 0; dm < 64; ++dm) {
      float wv = sw[t][dm];
      #pragma unroll
      for (int j = 0; j < 16; ++j)
        acc[j] += sx[lb * 16 + j][dm] * wv;
    }
    #pragma unroll
    for (int j = 0; j < 16; ++j)
      xz[obase + (size_t)(lb * 16 + j) * 256] = acc[j];
  }
}

// ---------------- K3: causal depthwise conv(4) + silu + x_dbl + softplus(dt) --
__global__ __launch_bounds__(256) void k3_convdt(const float* __restrict__ xz,
        const float* __restrict__ conv_w, const float* __restrict__ conv_b,
        const float* __restrict__ x_proj_w, const float* __restrict__ dt_proj_w,
        const float* __restrict__ dt_proj_b,
        float* __restrict__ xc, float* __restrict__ dt, float* __restrict__ bc) {
  __shared__ float sxp[67][128];
  __shared__ float sxc[64][128];
  __shared__ float sxw[36][129];
  __shared__ float sdb[64][36];
  __shared__ float scw[128][5];
  __shared__ float scb[128];
  __shared__ float sdw[128][5];
  __shared__ float sdpb[128];
  int t = threadIdx.x;
  int l0 = blockIdx.x * 64;
  int bp = blockIdx.z * P_ + blockIdx.y;
  const float* xzb = xz + (size_t)bp * L_ * 256;
  if (t < 128) {
    #pragma unroll
    for (int j = 0; j < 4; ++j) { scw[t][j] = conv_w[t * 4 + j]; sdw[t][j] = dt_proj_w[t * 4 + j]; }
    scb[t] = conv_b[t]; sdpb[t] = dt_proj_b[t];
  }
  for (int i = t; i < 36 * 128; i += 256) sxw[i >> 7][i & 127] = x_proj_w[i];
  for (int i = t; i < 67 * 128; i += 256) {
    int r = i >> 7, d = i & 127;
    int l = l0 - 3 + r;
    sxp[r][d] = (l >= 0) ? xzb[(size_t)l * 256 + d] : 0.f;
  }
  __syncthreads();
  for (int i = 0; i < 32; ++i) {
    int idx = t + 256 * i;
    int ll = idx >> 7, d = idx & 127;
    float cv = scb[d];
    #pragma unroll
    for (int j = 0; j < 4; ++j) cv += scw[d][j] * sxp[ll + j][d];
    float sv = cv / (1.f + __expf(-cv));
    sxc[ll][d] = sv;
    xc[((size_t)bp * L_ + l0 + ll) * 128 + d] = sv;
  }
  __syncthreads();
  for (int idx = t; idx < 64 * 36; idx += 256) {
    int ll = idx / 36, r = idx % 36;
    float acc = 0.f;
    #pragma unroll 8
    for (int d = 0; d < 128; ++d) acc += sxc[ll][d] * sxw[r][d];
    sdb[ll][r] = acc;
    if (r >= 4) bc[((size_t)bp * L_ + l0 + ll) * 32 + (r - 4)] = acc;
  }
  __syncthreads();
  for (int i = 0; i < 32; ++i) {
    int idx = t + 256 * i;
    int ll = idx >> 7, d = idx & 127;
    float v = sdpb[d];
    #pragma unroll
    for (int r = 0; r < 4; ++r) v += sdb[ll][r] * sdw[d][r];
    float sp = (v > 20.f) ? v : log1pf(__expf(v));
    dt[((size_t)bp * L_ + l0 + ll) * 128 + d] = sp;
  }
}

// ---------------- K4: scan pass A — per-chunk (prod dA, h_end | h0=0) --------
__global__ __launch_bounds__(256) void k4_scanA(const float* __restrict__ dt,
        const float* __restrict__ xc, const float* __restrict__ bcbuf,
        const float* __restrict__ A_log,
        float* __restrict__ chA, float* __restrict__ chH) {
  __shared__ float sdt[TS][16];
  __shared__ float sxc[TS][16];
  __shared__ float sB[TS][16];
  int t = threadIdx.x;
  int s = t & 15, dl = t >> 4;
  int ch = blockIdx.x, dblk = blockIdx.y, bp = blockIdx.z;
  int d0 = dblk * 16;
  int d = d0 + dl;
  float Av = -__expf(A_log[d * 16 + s]);
  float aprod = 1.f, h = 0.f;
  const float* dtb = dt + (size_t)bp * L_ * 128;
  const float* xcb = xc + (size_t)bp * L_ * 128;
  const float* bcb = bcbuf + (size_t)bp * L_ * 32;
  int tb0 = ch * CHL;
  for (int sub = 0; sub < CHL / TS; ++sub) {
    int tb = tb0 + sub * TS;
    __syncthreads();
    for (int i = 0; i < 4; ++i) {
      int idx = t + 256 * i;
      int tt = idx >> 4, col = idx & 15;
      sdt[tt][col] = dtb[(size_t)(tb + tt) * 128 + d0 + col];
      sxc[tt][col] = xcb[(size_t)(tb + tt) * 128 + d0 + col];
      sB[tt][col]  = bcb[(size_t)(tb + tt) * 32 + col];
    }
    __syncthreads();
    #pragma unroll 8
    for (int tt = 0; tt < TS; ++tt) {
      float dtv = sdt[tt][dl];
      float xcv = sxc[tt][dl];
      float bv  = sB[tt][s];
      float dA = __expf(dtv * Av);
      h = dA * h + dtv * xcv * bv;
      aprod *= dA;
    }
  }
  size_t o = (((size_t)bp * NCH + ch) * 128 + d) * 16 + s;
  chA[o] = aprod;
  chH[o] = h;
}

// ---------------- K5: scan pass B — prefix fold + y + gate --------------------
__global__ __launch_bounds__(256) void k5_scanB(const float* __restrict__ dt,
        const float* __restrict__ xc, const float* __restrict__ bcbuf,
        const float* __restrict__ xz, const float* __restrict__ A_log,
        const float* __restrict__ D_param,
        const float* __restrict__ chA, const float* __restrict__ chH,
        float* __restrict__ yg) {
  __shared__ float sdt[TS][16];
  __shared__ float sxc[TS][16];
  __shared__ float sB[TS][16];
  __shared__ float sC[TS][16];
  __shared__ float sZ[TS][16];
  __shared__ float sY[TS][16];
  int t = threadIdx.x;
  int s = t & 15, dl = t >> 4;
  int ch = blockIdx.x, dblk = blockIdx.y, bp = blockIdx.z;
  int d0 = dblk * 16;
  int d = d0 + dl;
  float Av = -__expf(A_log[d * 16 + s]);
  float Dv = D_param[d];
  float h = 0.f;
  {
    size_t base = ((size_t)bp * NCH * 128 + d) * 16 + s;
    for (int c = 0; c < ch; ++c) {
      size_t o = base + (size_t)c * 128 * 16;
      h = chA[o] * h + chH[o];
    }
  }
  const float* dtb = dt + (size_t)bp * L_ * 128;
  const float* xcb = xc + (size_t)bp * L_ * 128;
  const float* bcb = bcbuf + (size_t)bp * L_ * 32;
  const float* zb  = xz + (size_t)bp * L_ * 256 + 128;
  int tb0 = ch * CHL;
  for (int sub = 0; sub < CHL / TS; ++sub) {
    int tb = tb0 + sub * TS;
    __syncthreads();
    for (int i = 0; i < 4; ++i) {
      int idx = t + 256 * i;
      int tt = idx >> 4, col = idx & 15;
      sdt[tt][col] = dtb[(size_t)(tb + tt) * 128 + d0 + col];
      sxc[tt][col] = xcb[(size_t)(tb + tt) * 128 + d0 + col];
      sB[tt][col]  = bcb[(size_t)(tb + tt) * 32 + col];
      sC[tt][col]  = bcb[(size_t)(tb + tt) * 32 + 16 + col];
      sZ[tt][col]  = zb[(size_t)(tb + tt) * 256 + d0 + col];
    }
    __syncthreads();
    for (int tt = 0; tt < TS; ++tt) {
      float dtv = sdt[tt][dl];
      float xcv = sxc[tt][dl];
      float dA = __expf(dtv * Av);
      h = dA * h + dtv * xcv * sB[tt][s];
      float r = h * sC[tt][s];
      r += __shfl_xor(r, 1);
      r += __shfl_xor(r, 2);
      r += __shfl_xor(r, 4);
      r += __shfl_xor(r, 8);
      if (s == 0) {
        float yv = r + Dv * xcv;
        float zv = sZ[tt][dl];
        sY[tt][dl] = yv * (zv / (1.f + __expf(-zv)));
      }
    }
    __syncthreads();
    for (int i = 0; i < 4; ++i) {
      int idx = t + 256 * i;
      int tt = idx >> 4, col = idx & 15;
      yg[((size_t)bp * L_ + tb + tt) * 128 + d0 + col] = sY[tt][col];
    }
  }
}

// ---------------- K6a: out_proj + skip + LayerNorm2 --------------------------
__global__ __launch_bounds__(256) void k6a_outskip_ln(const float* __restrict__ yg,
        const float* __restrict__ xn, const float* __restrict__ opw,
        const float* __restrict__ skip, const float* __restrict__ g,
        const float* __restrict__ bb, float* __restrict__ xmn) {
  __shared__ float sw[64][129];
  __shared__ float syg[32][128];
  __shared__ float sxm[32][257];
  __shared__ float psum[8][32], psq[8][32], smu[32], srs[32];
  int t = threadIdx.x;
  int l0 = blockIdx.x * 32;
  int b = blockIdx.y;
  float sk = skip[0];
  for (int i = t; i < 64 * 128; i += 256) sw[i >> 7][i & 127] = opw[i];
  for (int p = 0; p < 4; ++p) {
    __syncthreads();
    for (int i = t; i < 32 * 128; i += 256) {
      int ll = i >> 7, dd = i & 127;
      syg[ll][dd] = yg[((size_t)(b * P_ + p) * L_ + l0 + ll) * 128 + dd];
    }
    __syncthreads();
    for (int i = 0; i < 8; ++i) {
      int idx = t + 256 * i;
      int ll = idx >> 6, m = idx & 63;
      float acc = 0.f;
      #pragma unroll 8
      for (int dd = 0; dd < 128; ++dd) acc += syg[ll][dd] * sw[m][dd];
      int c = p * 64 + m;
      sxm[ll][c] = acc + sk * xn[((size_t)b * L_ + l0 + ll) * 256 + c];
    }
  }
  __syncthreads();
  {
    int l = t & 31, k = t >> 5;
    float sum = 0.f, sq = 0.f;
    #pragma unroll 8
    for (int j = 0; j < 32; ++j) {
      float v = sxm[l][k * 32 + j];
      sum += v; sq += v * v;
    }
    psum[k][l] = sum; psq[k][l] = sq;
  }
  __syncthreads();
  if (t < 32) {
    float sum = 0.f, sq = 0.f;
    #pragma unroll
    for (int k = 0; k < 8; ++k) { sum += psum[k][t]; sq += psq[k][t]; }
    float mu = sum * (1.f / 256.f);
    smu[t] = mu;
    srs[t] = rsqrtf(sq * (1.f / 256.f) - mu * mu + 1e-5f);
  }
  __syncthreads();
  float gc = g[t], bcv = bb[t];
  for (int l = 0; l < 32; ++l) {
    float v = (sxm[l][t] - smu[l]) * srs[l] * gc + bcv;
    xmn[((size_t)b * L_ + l0 + l) * 256 + t] = v;
  }
}

// ---------------- K6b: out[b,o,l] = xmn[b,l,:] @ proj_w[o,:] + pb[o] ---------
__global__ __launch_bounds__(256) void k6b_proj(const float* __restrict__ xmn,
        const float* __restrict__ pw, const float* __restrict__ pb,
        float* __restrict__ out) {
  __shared__ float sa[64][65];
  __shared__ float sbw[64][65];
  int t = threadIdx.x;
  int l0 = blockIdx.x * 64;
  int o0 = blockIdx.y * 64;
  int b = blockIdx.z;
  int tl = t & 15, to = t >> 4;
  float acc[4][4];
  #pragma unroll
  for (int i = 0; i < 4; ++i)
    #pragma unroll
    for (int j = 0; j < 4; ++j) acc[i][j] = 0.f;
  for (int k0 = 0; k0 < 256; k0 += 64) {
    __syncthreads();
    for (int i = 0; i < 16; ++i) {
      int idx = t + 256 * i;
      int r = idx >> 6, cc = idx & 63;
      sa[r][cc]  = xmn[((size_t)b * L_ + l0 + r) * 256 + k0 + cc];
      sbw[r][cc] = pw[(size_t)(o0 + r) * 256 + k0 + cc];
    }
    __syncthreads();
    for (int cc = 0; cc < 64; ++cc) {
      float av[4], bv[4];
      #pragma unroll
      for (int il = 0; il < 4; ++il) av[il] = sa[4 * tl + il][cc];
      #pragma unroll
      for (int io = 0; io < 4; ++io) bv[io] = sbw[4 * to + io][cc];
      #pragma unroll
      for (int io = 0; io < 4; ++io)
        #pragma unroll
        for (int il = 0; il < 4; ++il)
          acc[io][il] += av[il] * bv[io];
    }
  }
  #pragma unroll
  for (int io = 0; io < 4; ++io) {
    int o = o0 + 4 * to + io;
    float bias = pb[o];
    float4 v = make_float4(acc[io][0] + bias, acc[io][1] + bias,
                           acc[io][2] + bias, acc[io][3] + bias);
    *(float4*)&out[((size_t)b * OUT_ + o) * L_ + l0 + 4 * tl] = v;
  }
}

extern "C" void kernel_launch(void* const* d_in, const int* in_sizes, int n_in,
                              void* d_out, int out_size, void* d_ws, size_t ws_size,
                              hipStream_t stream) {
  (void)in_sizes; (void)n_in; (void)out_size; (void)ws_size;
  const float* x          = (const float*)d_in[0];
  const float* ln_g       = (const float*)d_in[1];
  const float* ln_b       = (const float*)d_in[2];
  const float* in_proj_w  = (const float*)d_in[3];
  const float* conv_w     = (const float*)d_in[4];
  const float* conv_b     = (const float*)d_in[5];
  const float* x_proj_w   = (const float*)d_in[6];
  const float* dt_proj_w  = (const float*)d_in[7];
  const float* dt_proj_b  = (const float*)d_in[8];
  const float* A_log      = (const float*)d_in[9];
  const float* D_param    = (const float*)d_in[10];
  const float* out_proj_w = (const float*)d_in[11];
  const float* proj_w     = (const float*)d_in[12];
  const float* proj_b     = (const float*)d_in[13];
  const float* skip_scale = (const float*)d_in[14];

  float* ws  = (float*)d_ws;
  float* xn  = ws;              // 2,097,152 f
  float* xz  = xn + 2097152;    // 8,388,608 f
  float* xc  = xz + 8388608;    // 4,194,304 f
  float* dt  = xc + 4194304;    // 4,194,304 f
  float* bc  = dt + 4194304;    // 1,048,576 f
  float* chA = bc + 1048576;    // 2,097,152 f
  float* chH = chA + 2097152;   // 2,097,152 f
  float* yg  = chH + 2097152;   // 4,194,304 f
  float* xmn = yg + 4194304;    // 2,097,152 f  (total ~121.6 MB)
  float* out = (float*)d_out;

  k1_ln<<<dim3(L_ / 32, B_), 256, 0, stream>>>(x, ln_g, ln_b, xn);
  k2_inproj<<<dim3(L_ / 64, P_, B_), 256, 0, stream>>>(xn, in_proj_w, xz);
  k3_convdt<<<dim3(L_ / 64, P_, B_), 256, 0, stream>>>(xz, conv_w, conv_b,
      x_proj_w, dt_proj_w, dt_proj_b, xc, dt, bc);
  k4_scanA<<<dim3(NCH, DI_ / 16, B_ * P_), 256, 0, stream>>>(dt, xc, bc, A_log, chA, chH);
  k5_scanB<<<dim3(NCH, DI_ / 16, B_ * P_), 256, 0, stream>>>(dt, xc, bc, xz,
      A_log, D_param, chA, chH, yg);
  k6a_outskip_ln<<<dim3(L_ / 32, B_), 256, 0, stream>>>(yg, xn, out_proj_w,
      skip_scale, ln_g, ln_b, xmn);
  k6b_proj<<<dim3(L_ / 64, OUT_ / 64, B_), 256, 0, stream>>>(xmn, proj_w, proj_b, out);
}

// Round 2
// 235.673 us; speedup vs baseline: 1.7125x; 1.7125x over previous
//
#include <hip/hip_runtime.h>

// PetaloMixer: LN -> 4x shared-weight Mamba over parts -> skip -> LN -> proj
// B=2, C=256, L=4096, P=4, DM=64, DI=128, DS=16, DTR=4, OUT=256. fp32.
// Scan: chunked, NCH=128 chunks of CHL=32, thread-owns-d (16 s-states in regs).

#define B_    2
#define C_    256
#define L_    4096
#define P_    4
#define DM_   64
#define DI_   128
#define OUT_  256
#define NCH   128
#define CHL   32

// ---------------- K1: LayerNorm over C for (b,l), x is (b,c,l) ----------------
__global__ __launch_bounds__(256) void k1_ln(const float* __restrict__ x,
        const float* __restrict__ g, const float* __restrict__ bb,
        float* __restrict__ xn) {
  __shared__ float tile[256][33];
  __shared__ float psum[8][32];
  __shared__ float psq[8][32];
  __shared__ float smu[32], srs[32];
  int t = threadIdx.x;
  int l0 = blockIdx.x * 32;
  int b = blockIdx.y;
  const float* xb = x + (size_t)b * C_ * L_;
  int ll = t & 31, cr = t >> 5;
  for (int i = 0; i < 32; ++i) {
    int c = cr + 8 * i;
    tile[c][ll] = xb[(size_t)c * L_ + l0 + ll];
  }
  __syncthreads();
  {
    int l = t & 31, k = t >> 5;
    float s = 0.f, sq = 0.f;
    #pragma unroll 8
    for (int j = 0; j < 32; ++j) {
      float v = tile[32 * k + j][l];
      s += v; sq += v * v;
    }
    psum[k][l] = s; psq[k][l] = sq;
  }
  __syncthreads();
  if (t < 32) {
    float s = 0.f, sq = 0.f;
    #pragma unroll
    for (int k = 0; k < 8; ++k) { s += psum[k][t]; sq += psq[k][t]; }
    float mu = s * (1.f / 256.f);
    float var = sq * (1.f / 256.f) - mu * mu;
    smu[t] = mu;
    srs[t] = rsqrtf(var + 1e-5f);
  }
  __syncthreads();
  float gc = g[t], bc = bb[t];
  for (int l = 0; l < 32; ++l) {
    float v = (tile[t][l] - smu[l]) * srs[l] * gc + bc;
    xn[((size_t)b * L_ + l0 + l) * C_ + t] = v;
  }
}

// ---------------- K2: xz[bp,l,0:256] = xn_part[b,l,64] @ W(256x64)^T ---------
// Register-tiled: thread = (o-tile 4 along lanes, l-tile 16), f4 LDS reads.
__global__ __launch_bounds__(256) void k2_inproj(const float* __restrict__ xn,
        const float* __restrict__ w, float* __restrict__ xz) {
  __shared__ float swT[32 * 256];   // [k_local][o]
  __shared__ float sxT[32 * 64];    // [k_local][l]
  int t = threadIdx.x;
  int l0 = blockIdx.x * 64;
  int p = blockIdx.y, b = blockIdx.z;
  int to = t & 63, tl = t >> 6;
  float acc[4][16];
  #pragma unroll
  for (int io = 0; io < 4; ++io)
    #pragma unroll
    for (int il = 0; il < 16; ++il) acc[io][il] = 0.f;

  for (int kt = 0; kt < 2; ++kt) {
    __syncthreads();
    // stage swT: thread t = weight row o
    {
      const float* wr = w + (size_t)t * 64 + kt * 32;
      #pragma unroll
      for (int k4 = 0; k4 < 8; ++k4) {
        float4 v = *(const float4*)&wr[k4 * 4];
        swT[(k4 * 4 + 0) * 256 + t] = v.x;
        swT[(k4 * 4 + 1) * 256 + t] = v.y;
        swT[(k4 * 4 + 2) * 256 + t] = v.z;
        swT[(k4 * 4 + 3) * 256 + t] = v.w;
      }
    }
    // stage sxT: l = t&63, dg = t>>6 covers 8 dm each
    {
      int l = t & 63, dg = t >> 6;
      const float* xr = xn + ((size_t)b * L_ + l0 + l) * 256 + p * 64 + kt * 32 + dg * 8;
      #pragma unroll
      for (int jj = 0; jj < 2; ++jj) {
        float4 v = *(const float4*)&xr[jj * 4];
        sxT[(dg * 8 + jj * 4 + 0) * 64 + l] = v.x;
        sxT[(dg * 8 + jj * 4 + 1) * 64 + l] = v.y;
        sxT[(dg * 8 + jj * 4 + 2) * 64 + l] = v.z;
        sxT[(dg * 8 + jj * 4 + 3) * 64 + l] = v.w;
      }
    }
    __syncthreads();
    for (int k = 0; k < 32; ++k) {
      float4 b4 = *(const float4*)&swT[k * 256 + to * 4];
      #pragma unroll
      for (int q = 0; q < 4; ++q) {
        float4 a4 = *(const float4*)&sxT[k * 64 + tl * 16 + q * 4];
        acc[0][q*4+0] += b4.x * a4.x; acc[0][q*4+1] += b4.x * a4.y;
        acc[0][q*4+2] += b4.x * a4.z; acc[0][q*4+3] += b4.x * a4.w;
        acc[1][q*4+0] += b4.y * a4.x; acc[1][q*4+1] += b4.y * a4.y;
        acc[1][q*4+2] += b4.y * a4.z; acc[1][q*4+3] += b4.y * a4.w;
        acc[2][q*4+0] += b4.z * a4.x; acc[2][q*4+1] += b4.z * a4.y;
        acc[2][q*4+2] += b4.z * a4.z; acc[2][q*4+3] += b4.z * a4.w;
        acc[3][q*4+0] += b4.w * a4.x; acc[3][q*4+1] += b4.w * a4.y;
        acc[3][q*4+2] += b4.w * a4.z; acc[3][q*4+3] += b4.w * a4.w;
      }
    }
  }
  size_t ob = ((size_t)((b * 4 + p)) * L_ + l0 + tl * 16) * 256 + to * 4;
  #pragma unroll
  for (int il = 0; il < 16; ++il) {
    float4 v = make_float4(acc[0][il], acc[1][il], acc[2][il], acc[3][il]);
    *(float4*)&xz[ob + (size_t)il * 256] = v;
  }
}

// ---------------- K3: causal depthwise conv(4) + silu + x_dbl + softplus(dt) --
__global__ __launch_bounds__(256) void k3_convdt(const float* __restrict__ xz,
        const float* __restrict__ conv_w, const float* __restrict__ conv_b,
        const float* __restrict__ x_proj_w, const float* __restrict__ dt_proj_w,
        const float* __restrict__ dt_proj_b,
        float* __restrict__ xc, float* __restrict__ dt, float* __restrict__ bc) {
  __shared__ float uA[67 * 128];     // sxp, later reused for x_proj_w (36*128)
  __shared__ float sxcS[64 * 128];   // XOR-swizzled conv output
  __shared__ float sdb[64 * 5];      // dt partials (r<4)
  __shared__ float scw[128 * 5], sdw[128 * 5];
  __shared__ float scb[128], sdpb[128];
  int t = threadIdx.x;
  int l0 = blockIdx.x * 64;
  int bp = blockIdx.z * P_ + blockIdx.y;
  const float* xzb = xz + (size_t)bp * L_ * 256;
  if (t < 128) {
    #pragma unroll
    for (int j = 0; j < 4; ++j) { scw[t * 5 + j] = conv_w[t * 4 + j]; sdw[t * 5 + j] = dt_proj_w[t * 4 + j]; }
    scb[t] = conv_b[t]; sdpb[t] = dt_proj_b[t];
  }
  for (int i = t; i < 67 * 128; i += 256) {
    int r = i >> 7, d = i & 127;
    int l = l0 - 3 + r;
    uA[i] = (l >= 0) ? xzb[(size_t)l * 256 + d] : 0.f;
  }
  __syncthreads();
  // conv + silu
  for (int i = 0; i < 32; ++i) {
    int idx = t + 256 * i;
    int ll = idx >> 7, d = idx & 127;
    float cv = scb[d];
    #pragma unroll
    for (int j = 0; j < 4; ++j) cv += scw[d * 5 + j] * uA[(ll + j) * 128 + d];
    float sv = cv / (1.f + __expf(-cv));
    sxcS[ll * 128 + (d ^ (4 * (ll & 31)))] = sv;
    xc[((size_t)bp * L_ + l0 + ll) * 128 + d] = sv;
  }
  __syncthreads();
  // reuse uA for x_proj_w
  for (int i = t; i < 36 * 128; i += 256) uA[i] = x_proj_w[i];
  __syncthreads();
  // x_dbl: thread l = t&63, og = t>>6, outs og*9..og*9+8
  {
    int l = t & 63, og = t >> 6;
    float acc[9];
    #pragma unroll
    for (int rr = 0; rr < 9; ++rr) acc[rr] = 0.f;
    for (int k4 = 0; k4 < 32; ++k4) {
      float4 a4 = *(const float4*)&sxcS[l * 128 + ((k4 * 4) ^ (4 * (l & 31)))];
      #pragma unroll
      for (int rr = 0; rr < 9; ++rr) {
        float4 w4 = *(const float4*)&uA[(og * 9 + rr) * 128 + k4 * 4];
        acc[rr] += a4.x * w4.x + a4.y * w4.y + a4.z * w4.z + a4.w * w4.w;
      }
    }
    #pragma unroll
    for (int rr = 0; rr < 9; ++rr) {
      int ra = og * 9 + rr;
      if (ra < 4) sdb[l * 5 + ra] = acc[rr];
      else bc[((size_t)bp * L_ + l0 + l) * 32 + (ra - 4)] = acc[rr];
    }
  }
  __syncthreads();
  // dt = softplus(dt_partial @ dt_proj_w^T + b)
  for (int i = 0; i < 32; ++i) {
    int idx = t + 256 * i;
    int ll = idx >> 7, d = idx & 127;
    float v = sdpb[d];
    #pragma unroll
    for (int r = 0; r < 4; ++r) v += sdb[ll * 5 + r] * sdw[d * 5 + r];
    float sp = (v > 20.f) ? v : log1pf(__expf(v));
    dt[((size_t)bp * L_ + l0 + ll) * 128 + d] = sp;
  }
}

// ---------------- K4a: per-chunk (aprod, h_end | h0=0), thread owns d --------
__global__ __launch_bounds__(128) void k4a_scanA(const float* __restrict__ dt,
        const float* __restrict__ xc, const float* __restrict__ bcbuf,
        const float* __restrict__ A_log,
        float* __restrict__ chA, float* __restrict__ chH) {
  int d = threadIdx.x;
  int ch = blockIdx.x, bp = blockIdx.y;
  float Av[16], h[16];
  #pragma unroll
  for (int q = 0; q < 4; ++q) {
    float4 a = *(const float4*)&A_log[d * 16 + q * 4];
    Av[q*4+0] = -__expf(a.x); Av[q*4+1] = -__expf(a.y);
    Av[q*4+2] = -__expf(a.z); Av[q*4+3] = -__expf(a.w);
  }
  #pragma unroll
  for (int s = 0; s < 16; ++s) h[s] = 0.f;
  float sumdt = 0.f;
  const float* dtp = dt + (size_t)bp * L_ * 128 + (size_t)ch * CHL * 128 + d;
  const float* xcp = xc + (size_t)bp * L_ * 128 + (size_t)ch * CHL * 128 + d;
  const float* bcp = bcbuf + (size_t)bp * L_ * 32 + (size_t)ch * CHL * 32;
  #pragma unroll 2
  for (int tt = 0; tt < CHL; ++tt) {
    float dtv = dtp[tt * 128];
    float xcv = xcp[tt * 128];
    float Bv[16];
    *(float4*)&Bv[0]  = *(const float4*)&bcp[tt * 32 + 0];
    *(float4*)&Bv[4]  = *(const float4*)&bcp[tt * 32 + 4];
    *(float4*)&Bv[8]  = *(const float4*)&bcp[tt * 32 + 8];
    *(float4*)&Bv[12] = *(const float4*)&bcp[tt * 32 + 12];
    float w = dtv * xcv;
    sumdt += dtv;
    #pragma unroll
    for (int s = 0; s < 16; ++s) {
      float dA = __expf(dtv * Av[s]);
      h[s] = fmaf(dA, h[s], w * Bv[s]);
    }
  }
  size_t o = (((size_t)bp * NCH + ch) * 128 + d) * 16;
  #pragma unroll
  for (int s = 0; s < 16; ++s) chA[o + s] = __expf(sumdt * Av[s]);
  #pragma unroll
  for (int s = 0; s < 16; ++s) chH[o + s] = h[s];
}

// ---------------- K4b: exclusive scan over chunk states (in-place into chH) --
__global__ __launch_bounds__(256) void k4b_fold(const float* __restrict__ chA,
        float* __restrict__ chH) {
  int tid = blockIdx.x * 256 + threadIdx.x;   // 16384 threads
  int bp = tid >> 11;
  int rem = tid & 2047;
  float h = 0.f;
  for (int ch = 0; ch < NCH; ++ch) {
    size_t o = ((size_t)bp * NCH + ch) * 2048 + rem;
    float a = chA[o];
    float e = chH[o];
    chH[o] = h;            // exclusive prefix
    h = fmaf(a, h, e);
  }
}

// ---------------- K5: outputs — recurrence from h0, y, D-skip, silu(z) gate --
__global__ __launch_bounds__(128) void k5_scanB(const float* __restrict__ dt,
        const float* __restrict__ xc, const float* __restrict__ bcbuf,
        const float* __restrict__ xz, const float* __restrict__ A_log,
        const float* __restrict__ D_param, const float* __restrict__ chH,
        float* __restrict__ yg) {
  int d = threadIdx.x;
  int ch = blockIdx.x, bp = blockIdx.y;
  float Av[16], h[16];
  #pragma unroll
  for (int q = 0; q < 4; ++q) {
    float4 a = *(const float4*)&A_log[d * 16 + q * 4];
    Av[q*4+0] = -__expf(a.x); Av[q*4+1] = -__expf(a.y);
    Av[q*4+2] = -__expf(a.z); Av[q*4+3] = -__expf(a.w);
  }
  {
    size_t o = (((size_t)bp * NCH + ch) * 128 + d) * 16;
    #pragma unroll
    for (int q = 0; q < 4; ++q)
      *(float4*)&h[q * 4] = *(const float4*)&chH[o + q * 4];
  }
  float Dv = D_param[d];
  const float* dtp = dt + (size_t)bp * L_ * 128 + (size_t)ch * CHL * 128 + d;
  const float* xcp = xc + (size_t)bp * L_ * 128 + (size_t)ch * CHL * 128 + d;
  const float* bcp = bcbuf + (size_t)bp * L_ * 32 + (size_t)ch * CHL * 32;
  const float* zp  = xz + (size_t)bp * L_ * 256 + (size_t)ch * CHL * 256 + 128 + d;
  float* ygp = yg + (size_t)bp * L_ * 128 + (size_t)ch * CHL * 128 + d;
  #pragma unroll 2
  for (int tt = 0; tt < CHL; ++tt) {
    float dtv = dtp[tt * 128];
    float xcv = xcp[tt * 128];
    float zv  = zp[tt * 256];
    float Bv[16], Cv[16];
    *(float4*)&Bv[0]  = *(const float4*)&bcp[tt * 32 + 0];
    *(float4*)&Bv[4]  = *(const float4*)&bcp[tt * 32 + 4];
    *(float4*)&Bv[8]  = *(const float4*)&bcp[tt * 32 + 8];
    *(float4*)&Bv[12] = *(const float4*)&bcp[tt * 32 + 12];
    *(float4*)&Cv[0]  = *(const float4*)&bcp[tt * 32 + 16];
    *(float4*)&Cv[4]  = *(const float4*)&bcp[tt * 32 + 20];
    *(float4*)&Cv[8]  = *(const float4*)&bcp[tt * 32 + 24];
    *(float4*)&Cv[12] = *(const float4*)&bcp[tt * 32 + 28];
    float w = dtv * xcv;
    float r = 0.f;
    #pragma unroll
    for (int s = 0; s < 16; ++s) {
      float dA = __expf(dtv * Av[s]);
      h[s] = fmaf(dA, h[s], w * Bv[s]);
      r = fmaf(h[s], Cv[s], r);
    }
    float y = fmaf(Dv, xcv, r);
    float sig = 1.f / (1.f + __expf(-zv));
    ygp[tt * 128] = y * (zv * sig);
  }
}

// ---------------- K6a: out_proj + skip (no LN) -------------------------------
__global__ __launch_bounds__(256) void k6a_gemm(const float* __restrict__ yg,
        const float* __restrict__ xn, const float* __restrict__ opw,
        const float* __restrict__ skip, float* __restrict__ xmn) {
  __shared__ float sgT[128 * 64];   // [dd][l]
  __shared__ float swT2[128 * 64];  // [dd][m]
  int t = threadIdx.x;
  int l0 = blockIdx.x * 64;
  int p = blockIdx.y, b = blockIdx.z;
  int bp = b * 4 + p;
  float sk = skip[0];
  {
    int l = t & 63, dg = t >> 6;
    const float* yr = yg + ((size_t)bp * L_ + l0 + l) * 128 + dg * 32;
    const float* wr = opw + (size_t)l * 128 + dg * 32;   // l doubles as m-row
    #pragma unroll
    for (int jj = 0; jj < 8; ++jj) {
      float4 v = *(const float4*)&yr[jj * 4];
      int dd = dg * 32 + jj * 4;
      sgT[(dd + 0) * 64 + l] = v.x; sgT[(dd + 1) * 64 + l] = v.y;
      sgT[(dd + 2) * 64 + l] = v.z; sgT[(dd + 3) * 64 + l] = v.w;
      float4 u = *(const float4*)&wr[jj * 4];
      swT2[(dd + 0) * 64 + l] = u.x; swT2[(dd + 1) * 64 + l] = u.y;
      swT2[(dd + 2) * 64 + l] = u.z; swT2[(dd + 3) * 64 + l] = u.w;
    }
  }
  __syncthreads();
  int to = t & 15, tl = t >> 4;
  float acc[4][4];
  #pragma unroll
  for (int io = 0; io < 4; ++io)
    #pragma unroll
    for (int il = 0; il < 4; ++il) acc[io][il] = 0.f;
  for (int dd = 0; dd < 128; ++dd) {
    float4 a4 = *(const float4*)&sgT[dd * 64 + tl * 4];
    float4 b4 = *(const float4*)&swT2[dd * 64 + to * 4];
    acc[0][0] += b4.x * a4.x; acc[0][1] += b4.x * a4.y; acc[0][2] += b4.x * a4.z; acc[0][3] += b4.x * a4.w;
    acc[1][0] += b4.y * a4.x; acc[1][1] += b4.y * a4.y; acc[1][2] += b4.y * a4.z; acc[1][3] += b4.y * a4.w;
    acc[2][0] += b4.z * a4.x; acc[2][1] += b4.z * a4.y; acc[2][2] += b4.z * a4.z; acc[2][3] += b4.z * a4.w;
    acc[3][0] += b4.w * a4.x; acc[3][1] += b4.w * a4.y; acc[3][2] += b4.w * a4.z; acc[3][3] += b4.w * a4.w;
  }
  #pragma unroll
  for (int il = 0; il < 4; ++il) {
    size_t addr = ((size_t)b * L_ + l0 + tl * 4 + il) * 256 + p * 64 + to * 4;
    float4 xv = *(const float4*)&xn[addr];
    float4 v = make_float4(acc[0][il] + sk * xv.x, acc[1][il] + sk * xv.y,
                           acc[2][il] + sk * xv.z, acc[3][il] + sk * xv.w);
    *(float4*)&xmn[addr] = v;
  }
}

// ---------------- K6ln: row LayerNorm over C (rows contiguous), in-place -----
__global__ __launch_bounds__(256) void k6ln(float* __restrict__ xmn,
        const float* __restrict__ g, const float* __restrict__ bb) {
  int t = threadIdx.x;
  int row = blockIdx.x * 4 + (t >> 6);
  int lane = t & 63;
  float* rp = xmn + (size_t)row * 256 + lane * 4;
  float4 v = *(const float4*)rp;
  float s = v.x + v.y + v.z + v.w;
  float q = v.x * v.x + v.y * v.y + v.z * v.z + v.w * v.w;
  #pragma unroll
  for (int off = 1; off < 64; off <<= 1) {
    s += __shfl_xor(s, off);
    q += __shfl_xor(q, off);
  }
  float mu = s * (1.f / 256.f);
  float rs = rsqrtf(q * (1.f / 256.f) - mu * mu + 1e-5f);
  float4 g4 = *(const float4*)&g[lane * 4];
  float4 b4 = *(const float4*)&bb[lane * 4];
  float4 o = make_float4((v.x - mu) * rs * g4.x + b4.x,
                         (v.y - mu) * rs * g4.y + b4.y,
                         (v.z - mu) * rs * g4.z + b4.z,
                         (v.w - mu) * rs * g4.w + b4.w);
  *(float4*)rp = o;
}

// ---------------- K6b: out[b,o,l] = xmn[b,l,:] @ proj_w[o,:] + pb[o] ---------
__global__ __launch_bounds__(256) void k6b_proj(const float* __restrict__ xmn,
        const float* __restrict__ pw, const float* __restrict__ pb,
        float* __restrict__ out) {
  __shared__ float saT[64 * 64];   // [cc][l]
  __shared__ float sbT[64 * 64];   // [cc][o]
  int t = threadIdx.x;
  int l0 = blockIdx.x * 64;
  int o0 = blockIdx.y * 64;
  int b = blockIdx.z;
  int to = t & 15, tl = t >> 4;
  float acc[4][4];
  #pragma unroll
  for (int io = 0; io < 4; ++io)
    #pragma unroll
    for (int il = 0; il < 4; ++il) acc[io][il] = 0.f;
  for (int kt = 0; kt < 4; ++kt) {
    __syncthreads();
    {
      int l = t & 63, cg = t >> 6;
      const float* ar = xmn + ((size_t)b * L_ + l0 + l) * 256 + kt * 64 + cg * 16;
      const float* br = pw + (size_t)(o0 + l) * 256 + kt * 64 + cg * 16;
      #pragma unroll
      for (int jj = 0; jj < 4; ++jj) {
        float4 v = *(const float4*)&ar[jj * 4];
        int cc = cg * 16 + jj * 4;
        saT[(cc + 0) * 64 + l] = v.x; saT[(cc + 1) * 64 + l] = v.y;
        saT[(cc + 2) * 64 + l] = v.z; saT[(cc + 3) * 64 + l] = v.w;
        float4 u = *(const float4*)&br[jj * 4];
        sbT[(cc + 0) * 64 + l] = u.x; sbT[(cc + 1) * 64 + l] = u.y;
        sbT[(cc + 2) * 64 + l] = u.z; sbT[(cc + 3) * 64 + l] = u.w;
      }
    }
    __syncthreads();
    for (int cc = 0; cc < 64; ++cc) {
      float4 a4 = *(const float4*)&saT[cc * 64 + tl * 4];
      float4 b4 = *(const float4*)&sbT[cc * 64 + to * 4];
      acc[0][0] += b4.x * a4.x; acc[0][1] += b4.x * a4.y; acc[0][2] += b4.x * a4.z; acc[0][3] += b4.x * a4.w;
      acc[1][0] += b4.y * a4.x; acc[1][1] += b4.y * a4.y; acc[1][2] += b4.y * a4.z; acc[1][3] += b4.y * a4.w;
      acc[2][0] += b4.z * a4.x; acc[2][1] += b4.z * a4.y; acc[2][2] += b4.z * a4.z; acc[2][3] += b4.z * a4.w;
      acc[3][0] += b4.w * a4.x; acc[3][1] += b4.w * a4.y; acc[3][2] += b4.w * a4.z; acc[3][3] += b4.w * a4.w;
    }
  }
  #pragma unroll
  for (int io = 0; io < 4; ++io) {
    int o = o0 + to * 4 + io;
    float bias = pb[o];
    float4 v = make_float4(acc[io][0] + bias, acc[io][1] + bias,
                           acc[io][2] + bias, acc[io][3] + bias);
    *(float4*)&out[((size_t)b * OUT_ + o) * L_ + l0 + tl * 4] = v;
  }
}

extern "C" void kernel_launch(void* const* d_in, const int* in_sizes, int n_in,
                              void* d_out, int out_size, void* d_ws, size_t ws_size,
                              hipStream_t stream) {
  (void)in_sizes; (void)n_in; (void)out_size; (void)ws_size;
  const float* x          = (const float*)d_in[0];
  const float* ln_g       = (const float*)d_in[1];
  const float* ln_b       = (const float*)d_in[2];
  const float* in_proj_w  = (const float*)d_in[3];
  const float* conv_w     = (const float*)d_in[4];
  const float* conv_b     = (const float*)d_in[5];
  const float* x_proj_w   = (const float*)d_in[6];
  const float* dt_proj_w  = (const float*)d_in[7];
  const float* dt_proj_b  = (const float*)d_in[8];
  const float* A_log      = (const float*)d_in[9];
  const float* D_param    = (const float*)d_in[10];
  const float* out_proj_w = (const float*)d_in[11];
  const float* proj_w     = (const float*)d_in[12];
  const float* proj_b     = (const float*)d_in[13];
  const float* skip_scale = (const float*)d_in[14];

  float* ws  = (float*)d_ws;
  float* xn  = ws;              // 2,097,152 f
  float* xz  = xn + 2097152;    // 8,388,608 f
  float* xc  = xz + 8388608;    // 4,194,304 f
  float* dt  = xc + 4194304;    // 4,194,304 f
  float* bc  = dt + 4194304;    // 1,048,576 f
  float* chA = bc + 1048576;    // 2,097,152 f
  float* chH = chA + 2097152;   // 2,097,152 f  (k4b folds h0 in-place here)
  float* yg  = chH + 2097152;   // 4,194,304 f
  float* xmn = yg + 4194304;    // 2,097,152 f
  float* out = (float*)d_out;

  k1_ln<<<dim3(L_ / 32, B_), 256, 0, stream>>>(x, ln_g, ln_b, xn);
  k2_inproj<<<dim3(L_ / 64, P_, B_), 256, 0, stream>>>(xn, in_proj_w, xz);
  k3_convdt<<<dim3(L_ / 64, P_, B_), 256, 0, stream>>>(xz, conv_w, conv_b,
      x_proj_w, dt_proj_w, dt_proj_b, xc, dt, bc);
  k4a_scanA<<<dim3(NCH, B_ * P_), 128, 0, stream>>>(dt, xc, bc, A_log, chA, chH);
  k4b_fold<<<dim3(64), 256, 0, stream>>>(chA, chH);
  k5_scanB<<<dim3(NCH, B_ * P_), 128, 0, stream>>>(dt, xc, bc, xz, A_log,
      D_param, chH, yg);
  k6a_gemm<<<dim3(L_ / 64, P_, B_), 256, 0, stream>>>(yg, xn, out_proj_w,
      skip_scale, xmn);
  k6ln<<<dim3(B_ * L_ / 4), 256, 0, stream>>>(xmn, ln_g, ln_b);
  k6b_proj<<<dim3(L_ / 64, OUT_ / 64, B_), 256, 0, stream>>>(xmn, proj_w, proj_b, out);
}

// Round 3
// 234.592 us; speedup vs baseline: 1.7204x; 1.0046x over previous
//
#include <hip/hip_runtime.h>

// PetaloMixer: LN -> 4x shared-weight Mamba over parts -> skip -> LN -> proj
// B=2, C=256, L=4096, P=4, DM=64, DI=128, DS=16, DTR=4, OUT=256. fp32.
// Scan: chunked, NCH=128 chunks of CHL=32, thread-owns-d (16 s-states in regs).

#define B_    2
#define C_    256
#define L_    4096
#define P_    4
#define DM_   64
#define DI_   128
#define OUT_  256
#define NCH   128
#define CHL   32

// ---------------- K1: LayerNorm over C for (b,l), x is (b,c,l) ----------------
__global__ __launch_bounds__(256) void k1_ln(const float* __restrict__ x,
        const float* __restrict__ g, const float* __restrict__ bb,
        float* __restrict__ xn) {
  __shared__ float tile[256][33];
  __shared__ float psum[8][32];
  __shared__ float psq[8][32];
  __shared__ float smu[32], srs[32];
  int t = threadIdx.x;
  int l0 = blockIdx.x * 32;
  int b = blockIdx.y;
  const float* xb = x + (size_t)b * C_ * L_;
  int ll = t & 31, cr = t >> 5;
  for (int i = 0; i < 32; ++i) {
    int c = cr + 8 * i;
    tile[c][ll] = xb[(size_t)c * L_ + l0 + ll];
  }
  __syncthreads();
  {
    int l = t & 31, k = t >> 5;
    float s = 0.f, sq = 0.f;
    #pragma unroll 8
    for (int j = 0; j < 32; ++j) {
      float v = tile[32 * k + j][l];
      s += v; sq += v * v;
    }
    psum[k][l] = s; psq[k][l] = sq;
  }
  __syncthreads();
  if (t < 32) {
    float s = 0.f, sq = 0.f;
    #pragma unroll
    for (int k = 0; k < 8; ++k) { s += psum[k][t]; sq += psq[k][t]; }
    float mu = s * (1.f / 256.f);
    float var = sq * (1.f / 256.f) - mu * mu;
    smu[t] = mu;
    srs[t] = rsqrtf(var + 1e-5f);
  }
  __syncthreads();
  float gc = g[t], bc = bb[t];
  for (int l = 0; l < 32; ++l) {
    float v = (tile[t][l] - smu[l]) * srs[l] * gc + bc;
    xn[((size_t)b * L_ + l0 + l) * C_ + t] = v;
  }
}

// ---------------- K2: xz[bp,l,0:256] = xn_part[b,l,64] @ W(256x64)^T ---------
__global__ __launch_bounds__(256) void k2_inproj(const float* __restrict__ xn,
        const float* __restrict__ w, float* __restrict__ xz) {
  __shared__ float swT[32 * 256];   // [k_local][o]
  __shared__ float sxT[32 * 64];    // [k_local][l]
  int t = threadIdx.x;
  int l0 = blockIdx.x * 64;
  int p = blockIdx.y, b = blockIdx.z;
  int to = t & 63, tl = t >> 6;
  float acc[4][16];
  #pragma unroll
  for (int io = 0; io < 4; ++io)
    #pragma unroll
    for (int il = 0; il < 16; ++il) acc[io][il] = 0.f;

  for (int kt = 0; kt < 2; ++kt) {
    __syncthreads();
    {
      const float* wr = w + (size_t)t * 64 + kt * 32;
      #pragma unroll
      for (int k4 = 0; k4 < 8; ++k4) {
        float4 v = *(const float4*)&wr[k4 * 4];
        swT[(k4 * 4 + 0) * 256 + t] = v.x;
        swT[(k4 * 4 + 1) * 256 + t] = v.y;
        swT[(k4 * 4 + 2) * 256 + t] = v.z;
        swT[(k4 * 4 + 3) * 256 + t] = v.w;
      }
    }
    {
      int l = t & 63, dg = t >> 6;
      const float* xr = xn + ((size_t)b * L_ + l0 + l) * 256 + p * 64 + kt * 32 + dg * 8;
      #pragma unroll
      for (int jj = 0; jj < 2; ++jj) {
        float4 v = *(const float4*)&xr[jj * 4];
        sxT[(dg * 8 + jj * 4 + 0) * 64 + l] = v.x;
        sxT[(dg * 8 + jj * 4 + 1) * 64 + l] = v.y;
        sxT[(dg * 8 + jj * 4 + 2) * 64 + l] = v.z;
        sxT[(dg * 8 + jj * 4 + 3) * 64 + l] = v.w;
      }
    }
    __syncthreads();
    for (int k = 0; k < 32; ++k) {
      float4 b4 = *(const float4*)&swT[k * 256 + to * 4];
      #pragma unroll
      for (int q = 0; q < 4; ++q) {
        float4 a4 = *(const float4*)&sxT[k * 64 + tl * 16 + q * 4];
        acc[0][q*4+0] += b4.x * a4.x; acc[0][q*4+1] += b4.x * a4.y;
        acc[0][q*4+2] += b4.x * a4.z; acc[0][q*4+3] += b4.x * a4.w;
        acc[1][q*4+0] += b4.y * a4.x; acc[1][q*4+1] += b4.y * a4.y;
        acc[1][q*4+2] += b4.y * a4.z; acc[1][q*4+3] += b4.y * a4.w;
        acc[2][q*4+0] += b4.z * a4.x; acc[2][q*4+1] += b4.z * a4.y;
        acc[2][q*4+2] += b4.z * a4.z; acc[2][q*4+3] += b4.z * a4.w;
        acc[3][q*4+0] += b4.w * a4.x; acc[3][q*4+1] += b4.w * a4.y;
        acc[3][q*4+2] += b4.w * a4.z; acc[3][q*4+3] += b4.w * a4.w;
      }
    }
  }
  size_t ob = ((size_t)((b * 4 + p)) * L_ + l0 + tl * 16) * 256 + to * 4;
  #pragma unroll
  for (int il = 0; il < 16; ++il) {
    float4 v = make_float4(acc[0][il], acc[1][il], acc[2][il], acc[3][il]);
    *(float4*)&xz[ob + (size_t)il * 256] = v;
  }
}

// ---------------- K3 v2: fused conv+silu -> x_dbl -> dt, low-LDS --------------
// P0: conv from global with sliding regs; P1: weights via wave-uniform global
// loads (L1-resident), acts via swizzled LDS; P2: dt + coalesced bc writeout.
__global__ __launch_bounds__(256) void k3_convdt(const float* __restrict__ xz,
        const float* __restrict__ conv_w, const float* __restrict__ conv_b,
        const float* __restrict__ x_proj_w, const float* __restrict__ dt_proj_w,
        const float* __restrict__ dt_proj_b,
        float* __restrict__ xc, float* __restrict__ dt, float* __restrict__ bc) {
  __shared__ float sxc[64 * 128];   // conv out, [row][col ^ 4*(row&31)]
  __shared__ float sdb[64 * 5];     // dt partials (ra<4), padded stride 5
  __shared__ float sbc[64 * 33];    // B/C staging for coalesced writeout
  int t = threadIdx.x;
  int l0 = blockIdx.x * 64;
  int bp = blockIdx.z * P_ + blockIdx.y;
  const float* xzb = xz + (size_t)bp * L_ * 256;

  // ---- P0: causal conv(4) + silu, thread owns (d, half), 32 rows each ----
  {
    int d = t & 127, lh = t >> 7;
    int lstart = l0 + lh * 32;
    float4 cw = *(const float4*)&conv_w[d * 4];
    float cb = conv_b[d];
    float w0 = (lstart >= 3) ? xzb[(size_t)(lstart - 3) * 256 + d] : 0.f;
    float w1 = (lstart >= 2) ? xzb[(size_t)(lstart - 2) * 256 + d] : 0.f;
    float w2 = (lstart >= 1) ? xzb[(size_t)(lstart - 1) * 256 + d] : 0.f;
    float* xcrow = xc + ((size_t)bp * L_ + lstart) * 128 + d;
    const float* xzrow = xzb + (size_t)lstart * 256 + d;
    #pragma unroll 4
    for (int i = 0; i < 32; ++i) {
      float w3 = xzrow[(size_t)i * 256];
      float cv = cb + cw.x * w0 + cw.y * w1 + cw.z * w2 + cw.w * w3;
      float sv = cv / (1.f + __expf(-cv));
      int row = lh * 32 + i;
      sxc[row * 128 + (d ^ (4 * (row & 31)))] = sv;
      xcrow[(size_t)i * 128] = sv;
      w0 = w1; w1 = w2; w2 = w3;
    }
  }
  __syncthreads();
  // ---- P1: x_dbl = sxc(64x128) @ x_proj_w(36x128)^T; og wave-uniform ----
  {
    int l = t & 63, og = t >> 6;
    float acc[9];
    #pragma unroll
    for (int rr = 0; rr < 9; ++rr) acc[rr] = 0.f;
    const float* wbase = x_proj_w + og * 9 * 128;
    for (int k4 = 0; k4 < 32; ++k4) {
      float4 a4 = *(const float4*)&sxc[l * 128 + ((k4 * 4) ^ (4 * (l & 31)))];
      #pragma unroll
      for (int rr = 0; rr < 9; ++rr) {
        float4 w4 = *(const float4*)&wbase[rr * 128 + k4 * 4];
        acc[rr] += a4.x * w4.x + a4.y * w4.y + a4.z * w4.z + a4.w * w4.w;
      }
    }
    #pragma unroll
    for (int rr = 0; rr < 9; ++rr) {
      int ra = og * 9 + rr;
      if (ra < 4) sdb[l * 5 + ra] = acc[rr];
      else sbc[l * 33 + (ra - 4)] = acc[rr];
    }
  }
  __syncthreads();
  // ---- P2a: coalesced bc writeout ----
  #pragma unroll
  for (int i = 0; i < 8; ++i) {
    int idx = t + 256 * i;
    int row = idx >> 5, col = idx & 31;
    bc[((size_t)bp * L_ + l0 + row) * 32 + col] = sbc[row * 33 + col];
  }
  // ---- P2b: dt = softplus(partials @ dt_proj_w^T + b), thread owns d ----
  {
    int d = t & 127, lh = t >> 7;
    float4 dw = *(const float4*)&dt_proj_w[d * 4];
    float dpb = dt_proj_b[d];
    float* dtrow = dt + ((size_t)bp * L_ + l0 + lh * 32) * 128 + d;
    #pragma unroll 4
    for (int i = 0; i < 32; ++i) {
      int row = lh * 32 + i;
      float v = dpb + sdb[row * 5 + 0] * dw.x + sdb[row * 5 + 1] * dw.y
                    + sdb[row * 5 + 2] * dw.z + sdb[row * 5 + 3] * dw.w;
      float sp = (v > 20.f) ? v : log1pf(__expf(v));
      dtrow[(size_t)i * 128] = sp;
    }
  }
}

// ---------------- K4a: per-chunk (aprod, h_end | h0=0), thread owns d --------
__global__ __launch_bounds__(128) void k4a_scanA(const float* __restrict__ dt,
        const float* __restrict__ xc, const float* __restrict__ bcbuf,
        const float* __restrict__ A_log,
        float* __restrict__ chA, float* __restrict__ chH) {
  int d = threadIdx.x;
  int ch = blockIdx.x, bp = blockIdx.y;
  float Av[16], h[16];
  #pragma unroll
  for (int q = 0; q < 4; ++q) {
    float4 a = *(const float4*)&A_log[d * 16 + q * 4];
    Av[q*4+0] = -__expf(a.x); Av[q*4+1] = -__expf(a.y);
    Av[q*4+2] = -__expf(a.z); Av[q*4+3] = -__expf(a.w);
  }
  #pragma unroll
  for (int s = 0; s < 16; ++s) h[s] = 0.f;
  float sumdt = 0.f;
  const float* dtp = dt + (size_t)bp * L_ * 128 + (size_t)ch * CHL * 128 + d;
  const float* xcp = xc + (size_t)bp * L_ * 128 + (size_t)ch * CHL * 128 + d;
  const float* bcp = bcbuf + (size_t)bp * L_ * 32 + (size_t)ch * CHL * 32;
  #pragma unroll 2
  for (int tt = 0; tt < CHL; ++tt) {
    float dtv = dtp[tt * 128];
    float xcv = xcp[tt * 128];
    float Bv[16];
    *(float4*)&Bv[0]  = *(const float4*)&bcp[tt * 32 + 0];
    *(float4*)&Bv[4]  = *(const float4*)&bcp[tt * 32 + 4];
    *(float4*)&Bv[8]  = *(const float4*)&bcp[tt * 32 + 8];
    *(float4*)&Bv[12] = *(const float4*)&bcp[tt * 32 + 12];
    float w = dtv * xcv;
    sumdt += dtv;
    #pragma unroll
    for (int s = 0; s < 16; ++s) {
      float dA = __expf(dtv * Av[s]);
      h[s] = fmaf(dA, h[s], w * Bv[s]);
    }
  }
  size_t o = (((size_t)bp * NCH + ch) * 128 + d) * 16;
  #pragma unroll
  for (int s = 0; s < 16; ++s) chA[o + s] = __expf(sumdt * Av[s]);
  #pragma unroll
  for (int s = 0; s < 16; ++s) chH[o + s] = h[s];
}

// ---------------- K4b: exclusive scan over chunk states (in-place into chH) --
__global__ __launch_bounds__(256) void k4b_fold(const float* __restrict__ chA,
        float* __restrict__ chH) {
  int tid = blockIdx.x * 256 + threadIdx.x;   // 16384 threads
  int bp = tid >> 11;
  int rem = tid & 2047;
  float h = 0.f;
  for (int ch = 0; ch < NCH; ++ch) {
    size_t o = ((size_t)bp * NCH + ch) * 2048 + rem;
    float a = chA[o];
    float e = chH[o];
    chH[o] = h;            // exclusive prefix
    h = fmaf(a, h, e);
  }
}

// ---------------- K5: outputs — recurrence from h0, y, D-skip, silu(z) gate --
__global__ __launch_bounds__(128) void k5_scanB(const float* __restrict__ dt,
        const float* __restrict__ xc, const float* __restrict__ bcbuf,
        const float* __restrict__ xz, const float* __restrict__ A_log,
        const float* __restrict__ D_param, const float* __restrict__ chH,
        float* __restrict__ yg) {
  int d = threadIdx.x;
  int ch = blockIdx.x, bp = blockIdx.y;
  float Av[16], h[16];
  #pragma unroll
  for (int q = 0; q < 4; ++q) {
    float4 a = *(const float4*)&A_log[d * 16 + q * 4];
    Av[q*4+0] = -__expf(a.x); Av[q*4+1] = -__expf(a.y);
    Av[q*4+2] = -__expf(a.z); Av[q*4+3] = -__expf(a.w);
  }
  {
    size_t o = (((size_t)bp * NCH + ch) * 128 + d) * 16;
    #pragma unroll
    for (int q = 0; q < 4; ++q)
      *(float4*)&h[q * 4] = *(const float4*)&chH[o + q * 4];
  }
  float Dv = D_param[d];
  const float* dtp = dt + (size_t)bp * L_ * 128 + (size_t)ch * CHL * 128 + d;
  const float* xcp = xc + (size_t)bp * L_ * 128 + (size_t)ch * CHL * 128 + d;
  const float* bcp = bcbuf + (size_t)bp * L_ * 32 + (size_t)ch * CHL * 32;
  const float* zp  = xz + (size_t)bp * L_ * 256 + (size_t)ch * CHL * 256 + 128 + d;
  float* ygp = yg + (size_t)bp * L_ * 128 + (size_t)ch * CHL * 128 + d;
  #pragma unroll 2
  for (int tt = 0; tt < CHL; ++tt) {
    float dtv = dtp[tt * 128];
    float xcv = xcp[tt * 128];
    float zv  = zp[tt * 256];
    float Bv[16], Cv[16];
    *(float4*)&Bv[0]  = *(const float4*)&bcp[tt * 32 + 0];
    *(float4*)&Bv[4]  = *(const float4*)&bcp[tt * 32 + 4];
    *(float4*)&Bv[8]  = *(const float4*)&bcp[tt * 32 + 8];
    *(float4*)&Bv[12] = *(const float4*)&bcp[tt * 32 + 12];
    *(float4*)&Cv[0]  = *(const float4*)&bcp[tt * 32 + 16];
    *(float4*)&Cv[4]  = *(const float4*)&bcp[tt * 32 + 20];
    *(float4*)&Cv[8]  = *(const float4*)&bcp[tt * 32 + 24];
    *(float4*)&Cv[12] = *(const float4*)&bcp[tt * 32 + 28];
    float w = dtv * xcv;
    float r = 0.f;
    #pragma unroll
    for (int s = 0; s < 16; ++s) {
      float dA = __expf(dtv * Av[s]);
      h[s] = fmaf(dA, h[s], w * Bv[s]);
      r = fmaf(h[s], Cv[s], r);
    }
    float y = fmaf(Dv, xcv, r);
    float sig = 1.f / (1.f + __expf(-zv));
    ygp[tt * 128] = y * (zv * sig);
  }
}

// ---------------- K6a: out_proj + skip (no LN) -------------------------------
__global__ __launch_bounds__(256) void k6a_gemm(const float* __restrict__ yg,
        const float* __restrict__ xn, const float* __restrict__ opw,
        const float* __restrict__ skip, float* __restrict__ xmn) {
  __shared__ float sgT[128 * 64];   // [dd][l]
  __shared__ float swT2[128 * 64];  // [dd][m]
  int t = threadIdx.x;
  int l0 = blockIdx.x * 64;
  int p = blockIdx.y, b = blockIdx.z;
  int bp = b * 4 + p;
  float sk = skip[0];
  {
    int l = t & 63, dg = t >> 6;
    const float* yr = yg + ((size_t)bp * L_ + l0 + l) * 128 + dg * 32;
    const float* wr = opw + (size_t)l * 128 + dg * 32;   // l doubles as m-row
    #pragma unroll
    for (int jj = 0; jj < 8; ++jj) {
      float4 v = *(const float4*)&yr[jj * 4];
      int dd = dg * 32 + jj * 4;
      sgT[(dd + 0) * 64 + l] = v.x; sgT[(dd + 1) * 64 + l] = v.y;
      sgT[(dd + 2) * 64 + l] = v.z; sgT[(dd + 3) * 64 + l] = v.w;
      float4 u = *(const float4*)&wr[jj * 4];
      swT2[(dd + 0) * 64 + l] = u.x; swT2[(dd + 1) * 64 + l] = u.y;
      swT2[(dd + 2) * 64 + l] = u.z; swT2[(dd + 3) * 64 + l] = u.w;
    }
  }
  __syncthreads();
  int to = t & 15, tl = t >> 4;
  float acc[4][4];
  #pragma unroll
  for (int io = 0; io < 4; ++io)
    #pragma unroll
    for (int il = 0; il < 4; ++il) acc[io][il] = 0.f;
  for (int dd = 0; dd < 128; ++dd) {
    float4 a4 = *(const float4*)&sgT[dd * 64 + tl * 4];
    float4 b4 = *(const float4*)&swT2[dd * 64 + to * 4];
    acc[0][0] += b4.x * a4.x; acc[0][1] += b4.x * a4.y; acc[0][2] += b4.x * a4.z; acc[0][3] += b4.x * a4.w;
    acc[1][0] += b4.y * a4.x; acc[1][1] += b4.y * a4.y; acc[1][2] += b4.y * a4.z; acc[1][3] += b4.y * a4.w;
    acc[2][0] += b4.z * a4.x; acc[2][1] += b4.z * a4.y; acc[2][2] += b4.z * a4.z; acc[2][3] += b4.z * a4.w;
    acc[3][0] += b4.w * a4.x; acc[3][1] += b4.w * a4.y; acc[3][2] += b4.w * a4.z; acc[3][3] += b4.w * a4.w;
  }
  #pragma unroll
  for (int il = 0; il < 4; ++il) {
    size_t addr = ((size_t)b * L_ + l0 + tl * 4 + il) * 256 + p * 64 + to * 4;
    float4 xv = *(const float4*)&xn[addr];
    float4 v = make_float4(acc[0][il] + sk * xv.x, acc[1][il] + sk * xv.y,
                           acc[2][il] + sk * xv.z, acc[3][il] + sk * xv.w);
    *(float4*)&xmn[addr] = v;
  }
}

// ---------------- K6ln: row LayerNorm over C (rows contiguous), in-place -----
__global__ __launch_bounds__(256) void k6ln(float* __restrict__ xmn,
        const float* __restrict__ g, const float* __restrict__ bb) {
  int t = threadIdx.x;
  int row = blockIdx.x * 4 + (t >> 6);
  int lane = t & 63;
  float* rp = xmn + (size_t)row * 256 + lane * 4;
  float4 v = *(const float4*)rp;
  float s = v.x + v.y + v.z + v.w;
  float q = v.x * v.x + v.y * v.y + v.z * v.z + v.w * v.w;
  #pragma unroll
  for (int off = 1; off < 64; off <<= 1) {
    s += __shfl_xor(s, off);
    q += __shfl_xor(q, off);
  }
  float mu = s * (1.f / 256.f);
  float rs = rsqrtf(q * (1.f / 256.f) - mu * mu + 1e-5f);
  float4 g4 = *(const float4*)&g[lane * 4];
  float4 b4 = *(const float4*)&bb[lane * 4];
  float4 o = make_float4((v.x - mu) * rs * g4.x + b4.x,
                         (v.y - mu) * rs * g4.y + b4.y,
                         (v.z - mu) * rs * g4.z + b4.z,
                         (v.w - mu) * rs * g4.w + b4.w);
  *(float4*)rp = o;
}

// ---------------- K6b: out[b,o,l] = xmn[b,l,:] @ proj_w[o,:] + pb[o] ---------
__global__ __launch_bounds__(256) void k6b_proj(const float* __restrict__ xmn,
        const float* __restrict__ pw, const float* __restrict__ pb,
        float* __restrict__ out) {
  __shared__ float saT[64 * 64];   // [cc][l]
  __shared__ float sbT[64 * 64];   // [cc][o]
  int t = threadIdx.x;
  int l0 = blockIdx.x * 64;
  int o0 = blockIdx.y * 64;
  int b = blockIdx.z;
  int to = t & 15, tl = t >> 4;
  float acc[4][4];
  #pragma unroll
  for (int io = 0; io < 4; ++io)
    #pragma unroll
    for (int il = 0; il < 4; ++il) acc[io][il] = 0.f;
  for (int kt = 0; kt < 4; ++kt) {
    __syncthreads();
    {
      int l = t & 63, cg = t >> 6;
      const float* ar = xmn + ((size_t)b * L_ + l0 + l) * 256 + kt * 64 + cg * 16;
      const float* br = pw + (size_t)(o0 + l) * 256 + kt * 64 + cg * 16;
      #pragma unroll
      for (int jj = 0; jj < 4; ++jj) {
        float4 v = *(const float4*)&ar[jj * 4];
        int cc = cg * 16 + jj * 4;
        saT[(cc + 0) * 64 + l] = v.x; saT[(cc + 1) * 64 + l] = v.y;
        saT[(cc + 2) * 64 + l] = v.z; saT[(cc + 3) * 64 + l] = v.w;
        float4 u = *(const float4*)&br[jj * 4];
        sbT[(cc + 0) * 64 + l] = u.x; sbT[(cc + 1) * 64 + l] = u.y;
        sbT[(cc + 2) * 64 + l] = u.z; sbT[(cc + 3) * 64 + l] = u.w;
      }
    }
    __syncthreads();
    for (int cc = 0; cc < 64; ++cc) {
      float4 a4 = *(const float4*)&saT[cc * 64 + tl * 4];
      float4 b4 = *(const float4*)&sbT[cc * 64 + to * 4];
      acc[0][0] += b4.x * a4.x; acc[0][1] += b4.x * a4.y; acc[0][2] += b4.x * a4.z; acc[0][3] += b4.x * a4.w;
      acc[1][0] += b4.y * a4.x; acc[1][1] += b4.y * a4.y; acc[1][2] += b4.y * a4.z; acc[1][3] += b4.y * a4.w;
      acc[2][0] += b4.z * a4.x; acc[2][1] += b4.z * a4.y; acc[2][2] += b4.z * a4.z; acc[2][3] += b4.z * a4.w;
      acc[3][0] += b4.w * a4.x; acc[3][1] += b4.w * a4.y; acc[3][2] += b4.w * a4.z; acc[3][3] += b4.w * a4.w;
    }
  }
  #pragma unroll
  for (int io = 0; io < 4; ++io) {
    int o = o0 + to * 4 + io;
    float bias = pb[o];
    float4 v = make_float4(acc[io][0] + bias, acc[io][1] + bias,
                           acc[io][2] + bias, acc[io][3] + bias);
    *(float4*)&out[((size_t)b * OUT_ + o) * L_ + l0 + tl * 4] = v;
  }
}

extern "C" void kernel_launch(void* const* d_in, const int* in_sizes, int n_in,
                              void* d_out, int out_size, void* d_ws, size_t ws_size,
                              hipStream_t stream) {
  (void)in_sizes; (void)n_in; (void)out_size; (void)ws_size;
  const float* x          = (const float*)d_in[0];
  const float* ln_g       = (const float*)d_in[1];
  const float* ln_b       = (const float*)d_in[2];
  const float* in_proj_w  = (const float*)d_in[3];
  const float* conv_w     = (const float*)d_in[4];
  const float* conv_b     = (const float*)d_in[5];
  const float* x_proj_w   = (const float*)d_in[6];
  const float* dt_proj_w  = (const float*)d_in[7];
  const float* dt_proj_b  = (const float*)d_in[8];
  const float* A_log      = (const float*)d_in[9];
  const float* D_param    = (const float*)d_in[10];
  const float* out_proj_w = (const float*)d_in[11];
  const float* proj_w     = (const float*)d_in[12];
  const float* proj_b     = (const float*)d_in[13];
  const float* skip_scale = (const float*)d_in[14];

  float* ws  = (float*)d_ws;
  float* xn  = ws;              // 2,097,152 f
  float* xz  = xn + 2097152;    // 8,388,608 f
  float* xc  = xz + 8388608;    // 4,194,304 f
  float* dt  = xc + 4194304;    // 4,194,304 f
  float* bc  = dt + 4194304;    // 1,048,576 f
  float* chA = bc + 1048576;    // 2,097,152 f
  float* chH = chA + 2097152;   // 2,097,152 f  (k4b folds h0 in-place here)
  float* yg  = chH + 2097152;   // 4,194,304 f
  float* xmn = yg + 4194304;    // 2,097,152 f
  float* out = (float*)d_out;

  k1_ln<<<dim3(L_ / 32, B_), 256, 0, stream>>>(x, ln_g, ln_b, xn);
  k2_inproj<<<dim3(L_ / 64, P_, B_), 256, 0, stream>>>(xn, in_proj_w, xz);
  k3_convdt<<<dim3(L_ / 64, P_, B_), 256, 0, stream>>>(xz, conv_w, conv_b,
      x_proj_w, dt_proj_w, dt_proj_b, xc, dt, bc);
  k4a_scanA<<<dim3(NCH, B_ * P_), 128, 0, stream>>>(dt, xc, bc, A_log, chA, chH);
  k4b_fold<<<dim3(64), 256, 0, stream>>>(chA, chH);
  k5_scanB<<<dim3(NCH, B_ * P_), 128, 0, stream>>>(dt, xc, bc, xz, A_log,
      D_param, chH, yg);
  k6a_gemm<<<dim3(L_ / 64, P_, B_), 256, 0, stream>>>(yg, xn, out_proj_w,
      skip_scale, xmn);
  k6ln<<<dim3(B_ * L_ / 4), 256, 0, stream>>>(xmn, ln_g, ln_b);
  k6b_proj<<<dim3(L_ / 64, OUT_ / 64, B_), 256, 0, stream>>>(xmn, proj_w, proj_b, out);
}